// Round 14
// baseline (216.618 us; speedup 1.0000x reference)
//
#include <hip/hip_runtime.h>
#include <hip/hip_bf16.h>
#include <math.h>

#define B_   4
#define N_   6
#define CIN  512
#define CT   64
#define Dd   41
#define FH   16
#define FW   44
#define NPIX 704
#define NO   105
#define DSTR 48           // featD per-pixel stride
#define NXX  128
#define NYY  128
#define NZZ  1
#define TOT  (B_*NZZ*NYY*NXX)   // 65536
#define NPTS (B_*N_*Dd*NPIX)    // 692736
#define NCHUNK ((NPTS+63)/64)   // 10824

#define GEMM_BLOCKS 1056
#define GEOM_BLOCKS 4224
#define FUSED_BLOCKS (GEMM_BLOCKS + GEOM_BLOCKS)   // 5280

typedef __attribute__((ext_vector_type(8))) short short8;
typedef __attribute__((ext_vector_type(4))) float f32x4;

// ---------------- helpers ----------------

__device__ __forceinline__ unsigned short f2bf(float f) {   // RNE
    unsigned u = __float_as_uint(f);
    u += 0x7FFFu + ((u >> 16) & 1u);
    return (unsigned short)(u >> 16);
}

__device__ __forceinline__ void inv3(const double* m, double* o) {
    double a=m[0],b=m[1],c=m[2],d=m[3],e=m[4],f=m[5],g=m[6],h=m[7],i=m[8];
    double A  =  (e*i - f*h);
    double Bc = -(d*i - f*g);
    double Cc =  (d*h - e*g);
    double det = a*A + b*Bc + c*Cc;
    double inv = 1.0/det;
    o[0]=A*inv;            o[1]=-(b*i - c*h)*inv;  o[2]= (b*f - c*e)*inv;
    o[3]=Bc*inv;           o[4]= (a*i - c*g)*inv;  o[5]=-(a*f - c*d)*inv;
    o[6]=Cc*inv;           o[7]=-(a*h - b*g)*inv;  o[8]= (a*e - b*d)*inv;
}

// geometry for lane l (= depth) of pixel pix, camera bn. returns kept/vox.
__device__ __forceinline__ void geom_lane(const double* s_tf, int b, int pix, int l,
                                          bool& kept, int& vox) {
    const int hh = pix / FW, ww = pix % FW;
    const double fx = (double)((float)(ww * (703.0/43.0)));
    const double fy = (double)((float)(hh * 17.0));
    const double px = fx - s_tf[21], py = fy - s_tf[22], mz = -s_tf[23];
    const double qx0 = s_tf[ 9]*px + s_tf[10]*py + s_tf[11]*mz, qx1 = s_tf[11];
    const double qy0 = s_tf[12]*px + s_tf[13]*py + s_tf[14]*mz, qy1 = s_tf[14];
    const double qz0 = s_tf[15]*px + s_tf[16]*py + s_tf[17]*mz, qz1 = s_tf[17];
    const double ux0 = s_tf[0]*qx0 + s_tf[1]*qy0 + s_tf[2], ux1 = s_tf[0]*qx1 + s_tf[1]*qy1;
    const double uy0 = s_tf[3]*qx0 + s_tf[4]*qy0 + s_tf[5], uy1 = s_tf[3]*qx1 + s_tf[4]*qy1;
    const double uz0 = s_tf[6]*qx0 + s_tf[7]*qy0 + s_tf[8], uz1 = s_tf[6]*qx1 + s_tf[7]*qy1;
    const double t0 = s_tf[18], t1 = s_tf[19], t2 = s_tf[20];

    const double DXD = (double)0.8f;
    const double LOX = (double)(-50.8f) - DXD*0.5;
    const double LOY = LOX;
    const double DZD = 20.0;
    const double LOZ = -10.0;

    kept = false; vox = 0;
    if (l < Dd) {
        double fz = 4.0 + (double)l;
        double qz = qz0 + qz1*fz;
        double sx = qz*(ux0 + ux1*fz) + t0;
        double sy = qz*(uy0 + uy1*fz) + t1;
        double sz = qz*(uz0 + uz1*fz) + t2;
        int gx = (int)((sx - LOX) / DXD);
        int gy = (int)((sy - LOY) / DXD);
        int gz = (int)((sz - LOZ) / DZD);
        kept = (gx>=0) & (gx<NXX) & (gy>=0) & (gy<NYY) & (gz>=0) & (gz<NZZ);
        vox  = (((b*NZZ + gz)*NYY + gy)*NXX + gx);
    }
}

// ---------------- kernel P: prep = x->bf16 fragment layout + Wd->bf16 + tf --------
__global__ __launch_bounds__(256) void prep_kernel(
    const float* __restrict__ rots, const float* __restrict__ trans,
    const float* __restrict__ intrins, const float* __restrict__ post_rots,
    const float* __restrict__ post_trans, const float* __restrict__ Wd,
    const float* __restrict__ x,
    double* __restrict__ tf, unsigned short* __restrict__ WdB,
    unsigned short* __restrict__ xB)
{
    const int t = threadIdx.x;
    if (blockIdx.x < 2112) {
        __shared__ float s_x[64*68];          // stride 68: 16B-aligned float4 cells
        const int p    = blockIdx.x;
        const int bn   = p / 88;
        const int r    = p % 88;
        const int kg   = r / 11;          // 0..7 (64 k each)
        const int tile = r % 11;
        const int pix0 = tile * 64;

        const float* src = x + ((size_t)bn*CIN + kg*64)*NPIX + pix0;
        #pragma unroll
        for (int i = 0; i < 4; i++) {
            int idx = i*256 + t;          // 0..1023
            int k   = idx >> 4;
            int px4 = (idx & 15) * 4;
            float4 v = *(const float4*)&src[(size_t)k*NPIX + px4];
            *(float4*)&s_x[k*68 + px4] = v;
        }
        __syncthreads();

        const int px  = t & 63;
        #pragma unroll
        for (int pass = 0; pass < 2; pass++) {
            int k8l = (t >> 6) + 4*pass;          // 0..7
            unsigned pk[4];
            #pragma unroll
            for (int i = 0; i < 4; i++) {
                float a = s_x[(k8l*8 + 2*i    )*68 + px];
                float c = s_x[(k8l*8 + 2*i + 1)*68 + px];
                pk[i] = (unsigned)f2bf(a) | ((unsigned)f2bf(c) << 16);
            }
            unsigned* dst = (unsigned*)&xB[(((size_t)(bn*64 + kg*8 + k8l))*NPIX + pix0 + px)*8];
            *(uint4*)dst = make_uint4(pk[0], pk[1], pk[2], pk[3]);
        }
    } else {
        int b2 = blockIdx.x - 2112;
        int idx = b2*256 + t;
        if (idx < 128*CIN) {
            int o = idx / CIN;
            WdB[idx] = (o < NO) ? f2bf(Wd[idx]) : (unsigned short)0;
        }
        if (b2 == 0 && t < B_*N_) {
            int bn = t;
            double k[9], pr[9], r[9], ik[9], ipr[9], c[9];
            for (int i=0;i<9;i++) { k[i]=intrins[bn*9+i]; pr[i]=post_rots[bn*9+i]; r[i]=rots[bn*9+i]; }
            inv3(k, ik);
            inv3(pr, ipr);
            for (int i=0;i<3;i++)
                for (int j=0;j<3;j++) {
                    double s = 0.0;
                    for (int kk=0;kk<3;kk++) s += r[i*3+kk]*ik[kk*3+j];
                    c[i*3+j] = s;
                }
            double* o = tf + bn*24;
            for (int i=0;i<9;i++) o[i]   = c[i];
            for (int i=0;i<9;i++) o[9+i] = ipr[i];
            for (int i=0;i<3;i++) o[18+i] = (double)trans[bn*3+i];
            for (int i=0;i<3;i++) o[21+i] = (double)post_trans[bn*3+i];
        }
    }
}

// ---------------- kernel GG: fused bf16 MFMA GEMM || geometry+hist ----------------
// bid%5==0 -> gemm (LDS-free, barrier-free; weights via L1/L2-hot global loads).
// else     -> geometry + hist (fabric-atomic-bound). Uniform temporal interleave;
// LDS = 192 B total so occupancy is VGPR-limited, maximizing co-resident waves.
__global__ __launch_bounds__(256) void gemm_geom_kernel(
    const unsigned short* __restrict__ xB, const unsigned short* __restrict__ WdB,
    const float* __restrict__ bd, const double* __restrict__ tf,
    float* __restrict__ featD, float* __restrict__ featB,
    int* __restrict__ hist, int* __restrict__ rank_arr)
{
    __shared__ double s_tf[24];                   // geom path only

    const int t    = threadIdx.x;
    const int l    = t & 63;
    const int wv   = t >> 6;
    const int bidx = blockIdx.x;

    if (bidx % 5 == 0) {
        // ================= GEMM path =================
        const int gb   = bidx / 5;           // 0..1055
        const int col  = l & 15;
        const int quad = l >> 4;
        const int xcd = gb & 7;
        const int q   = gb >> 3;
        const int s   = q & 3;               // osplit
        const int pg  = q >> 2;
        const int p   = pg*8 + xcd;          // 0..263
        const int bn   = p / 11;
        const int tile = p % 11;
        const int pix0 = tile * 64;

        f32x4 acc[2];
        acc[0] = (f32x4){0.f,0.f,0.f,0.f};
        acc[1] = (f32x4){0.f,0.f,0.f,0.f};

        const int pix = pix0 + wv*16 + col;
        const unsigned short* xbase = xB + (((size_t)(bn*64))*NPIX)*8;
        const unsigned short* wb0 = WdB + (size_t)(s*32 +  0 + col)*CIN + quad*8;
        const unsigned short* wb1 = WdB + (size_t)(s*32 + 16 + col)*CIN + quad*8;

        #pragma unroll
        for (int ks = 0; ks < 16; ks++) {
            const int k8 = ks*4 + quad;
            short8 bfr = *(const short8*)&xbase[((size_t)k8*NPIX + pix)*8];
            short8 a0  = *(const short8*)&wb0[ks*32];
            short8 a1  = *(const short8*)&wb1[ks*32];
            acc[0] = __builtin_amdgcn_mfma_f32_16x16x32_bf16(a0, bfr, acc[0], 0, 0, 0);
            acc[1] = __builtin_amdgcn_mfma_f32_16x16x32_bf16(a1, bfr, acc[1], 0, 0, 0);
        }

        const size_t prow = (size_t)(bn*NPIX + pix);
        #pragma unroll
        for (int j = 0; j < 2; j++) {
            #pragma unroll
            for (int rr = 0; rr < 4; rr++) {
                int o = (2*s + j)*16 + quad*4 + rr;
                if (o < Dd) {
                    featD[prow*DSTR + o] = acc[j][rr] + bd[o];
                } else if (o < NO) {
                    featB[prow*CT + (o - Dd)] = acc[j][rr] + bd[o];
                }
            }
        }
    } else {
        // ================= geometry + hist path =================
        const int bid2 = bidx - (bidx/5) - 1;                      // 0..4223
        const int bid  = (bid2 & 7) * 528 + (bid2 >> 3);           // XCD locality
        const int bn  = bid / 176;
        const int pix = (bid % 176)*4 + wv;
        const int b   = bn / N_;

        if (t < 24) s_tf[t] = tf[bn*24 + t];
        __syncthreads();

        bool kept; int vox;
        geom_lane(s_tf, b, pix, l, kept, vox);
        if (kept) {
            int rank = atomicAdd(&hist[vox], 1);
            rank_arr[(size_t)(bn*NPIX + pix)*Dd + l] = rank;
        }
    }
}

// ---------------- scan: 256-block local scan + 1-block scan of block sums ---------
__global__ __launch_bounds__(256) void scan1_kernel(const int* __restrict__ hist,
                                                    int* __restrict__ offs,
                                                    int* __restrict__ bsum) {
    __shared__ int s[256];
    const int t = threadIdx.x;
    const int i = blockIdx.x*256 + t;
    int val = hist[i];
    s[t] = val;
    __syncthreads();
    #pragma unroll
    for (int off = 1; off < 256; off <<= 1) {
        int u = (t >= off) ? s[t-off] : 0;
        __syncthreads();
        s[t] += u;
        __syncthreads();
    }
    offs[i] = s[t] - val;                  // block-local exclusive
    if (t == 255) bsum[blockIdx.x] = s[255];
}

__global__ __launch_bounds__(256) void scan2_kernel(int* __restrict__ bsum,
                                                    int* __restrict__ np) {
    __shared__ int s[256];
    const int t = threadIdx.x;
    int v = bsum[t];
    s[t] = v;
    __syncthreads();
    #pragma unroll
    for (int off = 1; off < 256; off <<= 1) {
        int u = (t >= off) ? s[t-off] : 0;
        __syncthreads();
        s[t] += u;
        __syncthreads();
    }
    bsum[t] = s[t] - v;
    if (t == 255) np[0] = s[255];
}

// ---------------- kernel S2: softmax + geometry + atomic-free record scatter --------
__global__ __launch_bounds__(256) void sm_scatter_kernel(
    const float* __restrict__ featD, const double* __restrict__ tf,
    const int* __restrict__ offs, const int* __restrict__ bsum,
    const int* __restrict__ rank_arr, uint2* __restrict__ rec)
{
    __shared__ double s_tf[24];
    const int bid = (blockIdx.x & 7) * 528 + (blockIdx.x >> 3);   // XCD locality
    const int t   = threadIdx.x;
    const int l   = t & 63;
    const int wv  = t >> 6;
    const int bn  = bid / 176;
    const int pix = (bid % 176)*4 + wv;
    const int b   = bn / N_;

    if (t < 24) s_tf[t] = tf[bn*24 + t];
    __syncthreads();

    const size_t prow = (size_t)(bn*NPIX + pix);

    // ---- softmax across lanes (d = lane, 41 active) ----
    float logit = (l < Dd) ? featD[prow*DSTR + l] : -3.0e38f;
    float mm = logit;
    #pragma unroll
    for (int off = 32; off > 0; off >>= 1) mm = fmaxf(mm, __shfl_xor(mm, off));
    float e = (l < Dd) ? expf(logit - mm) : 0.0f;
    float ssum = e;
    #pragma unroll
    for (int off = 32; off > 0; off >>= 1) ssum += __shfl_xor(ssum, off);
    const float wgt = e / ssum;

    // ---- geometry + position from offs + bsum + rank (no atomics) ----
    bool kept; int vox;
    geom_lane(s_tf, b, pix, l, kept, vox);
    if (kept) {
        int pos = offs[vox] + bsum[vox >> 8] + rank_arr[prow*Dd + l];
        unsigned pk = ((unsigned)vox << 15) | (unsigned)prow;
        rec[pos] = make_uint2(pk, __float_as_uint(wgt));
    }
}

// ---------------- kernel E: balanced segmented gather -> scat[vox][ct] ----------------
__global__ __launch_bounds__(256) void gather_kernel(
    const uint2* __restrict__ rec, const int* __restrict__ np,
    const float* __restrict__ featB, float* __restrict__ scat)
{
    const int bid = (blockIdx.x & 7) * 339 + (blockIdx.x >> 3);   // XCD locality
    const int t  = threadIdx.x;
    const int wv = t >> 6;
    const int l  = t & 63;
    const int chunk = bid * 4 + wv;
    const int base  = chunk * 64;
    const int Np = np[0];                  // total valid points
    if (base >= Np) return;
    int cnt = Np - base; if (cnt > 64) cnt = 64;

    unsigned pk = 0; float w = 0.0f;
    if (l < cnt) { uint2 r = rec[base + l]; pk = r.x; w = __uint_as_float(r.y); }
    unsigned pkm = __shfl(pk, (l == 0) ? 0 : (l - 1));
    unsigned long long starts =
        __ballot((l > 0) && (l < cnt) && ((pk >> 15) != (pkm >> 15)));

    unsigned long long m = starts;
    int rs = 0;
    while (rs < cnt) {
        int re = m ? (__ffsll((unsigned long long)m) - 1) : cnt;
        if (m) m &= m - 1;
        float acc = 0.0f;
        for (int j = rs; j < re; j++) {
            unsigned pkj = __shfl(pk, j);
            float    wj  = __shfl(w, j);
            unsigned id  = pkj & 0x7FFFu;
            acc += wj * featB[(size_t)id * CT + l];
        }
        unsigned vrun = __shfl(pk, rs) >> 15;
        float* dst = scat + (size_t)vrun * CT + l;
        if (rs == 0 || re == cnt) {
            unsafeAtomicAdd(dst, acc);      // run may continue in adjacent chunk
        } else {
            *dst = acc;                     // voxel wholly owned by this chunk
        }
        rs = re;
    }
}

// ---------------- kernel F: transpose (b,pix,ct) -> (b,ct,pix) ----------------
__global__ __launch_bounds__(256) void transpose_k(const float* __restrict__ scat,
                                                   float* __restrict__ out) {
    __shared__ float tile[64][65];
    int b  = blockIdx.x >> 8;
    int t0 = (blockIdx.x & 255) * 64;
    const float* src = scat + (size_t)b * (NYY*NXX) * CT;
    #pragma unroll
    for (int i=0;i<16;i++) {
        int idx = threadIdx.x + i*256;
        int p = idx >> 6, c = idx & 63;
        tile[p][c] = src[(size_t)(t0+p)*CT + c];
    }
    __syncthreads();
    float* dst = out + (size_t)b * CT * (NYY*NXX);
    #pragma unroll
    for (int i=0;i<16;i++) {
        int idx = threadIdx.x + i*256;
        int c = idx >> 6, p = idx & 63;
        dst[(size_t)c*(NYY*NXX) + t0 + p] = tile[p][c];
    }
}

// ---------------- launcher ----------------
extern "C" void kernel_launch(void* const* d_in, const int* in_sizes, int n_in,
                              void* d_out, int out_size, void* d_ws, size_t ws_size,
                              hipStream_t stream) {
    const float* x          = (const float*)d_in[0];
    const float* rots       = (const float*)d_in[1];
    const float* trans      = (const float*)d_in[2];
    const float* intrins    = (const float*)d_in[3];
    const float* post_rots  = (const float*)d_in[4];
    const float* post_trans = (const float*)d_in[5];
    const float* Wd         = (const float*)d_in[6];
    const float* bd         = (const float*)d_in[7];
    float* out = (float*)d_out;

    char* ws = (char*)d_ws;
    float*          featB  = (float*)ws;          ws += (size_t)B_*N_*NPIX*CT*4;    // 4.33 MB
    float*          featD  = (float*)ws;          ws += (size_t)B_*N_*NPIX*DSTR*4;  // 3.25 MB
    char*           Xreg   = ws;                  ws += (size_t)B_*N_*CIN*NPIX*2;   // 17.3 MB (xB, then scat)
    int*            rank_a = (int*)ws;            ws += (size_t)NPTS*4;             // 2.77 MB
    uint2*          rec    = (uint2*)ws;          ws += (size_t)NPTS*8;             // 5.54 MB
    int*            hist   = (int*)ws;            ws += (size_t)TOT*4;              // 0.26 MB
    int*            offs   = (int*)ws;            ws += (size_t)TOT*4;              // 0.26 MB
    int*            bsum   = (int*)ws;            ws += 256*4;
    int*            np     = (int*)ws;            ws += 256;
    double*         tf     = (double*)ws;         ws += (size_t)B_*N_*24*8;         // 4.6 KB
    unsigned short* WdB    = (unsigned short*)ws; ws += (size_t)128*CIN*2;          // 0.13 MB

    unsigned short* xB   = (unsigned short*)Xreg;
    float*          scat = (float*)Xreg;   // reuses xB region after fused kernel

    hipMemsetAsync(hist, 0, (size_t)TOT*4, stream);
    prep_kernel<<<2368, 256, 0, stream>>>(rots, trans, intrins, post_rots, post_trans,
                                          Wd, x, tf, WdB, xB);
    gemm_geom_kernel<<<FUSED_BLOCKS, 256, 0, stream>>>(
        xB, WdB, bd, tf, featD, featB, hist, rank_a);
    hipMemsetAsync(scat, 0, (size_t)TOT*CT*4, stream);      // xB dead after fused
    scan1_kernel<<<TOT/256, 256, 0, stream>>>(hist, offs, bsum);
    scan2_kernel<<<1, 256, 0, stream>>>(bsum, np);
    sm_scatter_kernel<<<B_*N_*176, 256, 0, stream>>>(featD, tf, offs, bsum, rank_a, rec);
    gather_kernel<<<2712, 256, 0, stream>>>(rec, np, featB, scat);
    transpose_k<<<B_*(NYY*NXX/64), 256, 0, stream>>>(scat, out);
}

// Round 15
// 206.079 us; speedup vs baseline: 1.0511x; 1.0511x over previous
//
#include <hip/hip_runtime.h>
#include <hip/hip_bf16.h>
#include <math.h>

#define B_   4
#define N_   6
#define CIN  512
#define CT   64
#define Dd   41
#define FH   16
#define FW   44
#define NPIX 704
#define NO   105
#define DSTR 48           // featD per-pixel stride
#define NXX  128
#define NYY  128
#define NZZ  1
#define TOT  (B_*NZZ*NYY*NXX)   // 65536
#define NPTS (B_*N_*Dd*NPIX)    // 692736
#define NCHUNK ((NPTS+63)/64)   // 10824

#define WSTRIDE 520  // bf16 elems per s_wd row (512 + 8 pad)

#define GEMM_BLOCKS 1056
#define GEOM_BLOCKS 4224

typedef __attribute__((ext_vector_type(8))) short short8;
typedef __attribute__((ext_vector_type(4))) float f32x4;

// ---------------- helpers ----------------

__device__ __forceinline__ unsigned short f2bf(float f) {   // RNE
    unsigned u = __float_as_uint(f);
    u += 0x7FFFu + ((u >> 16) & 1u);
    return (unsigned short)(u >> 16);
}

__device__ __forceinline__ void inv3(const double* m, double* o) {
    double a=m[0],b=m[1],c=m[2],d=m[3],e=m[4],f=m[5],g=m[6],h=m[7],i=m[8];
    double A  =  (e*i - f*h);
    double Bc = -(d*i - f*g);
    double Cc =  (d*h - e*g);
    double det = a*A + b*Bc + c*Cc;
    double inv = 1.0/det;
    o[0]=A*inv;            o[1]=-(b*i - c*h)*inv;  o[2]= (b*f - c*e)*inv;
    o[3]=Bc*inv;           o[4]= (a*i - c*g)*inv;  o[5]=-(a*f - c*d)*inv;
    o[6]=Cc*inv;           o[7]=-(a*h - b*g)*inv;  o[8]= (a*e - b*d)*inv;
}

// geometry for lane l (= depth) of pixel pix, camera bn. returns kept/vox.
__device__ __forceinline__ void geom_lane(const double* s_tf, int b, int pix, int l,
                                          bool& kept, int& vox) {
    const int hh = pix / FW, ww = pix % FW;
    const double fx = (double)((float)(ww * (703.0/43.0)));
    const double fy = (double)((float)(hh * 17.0));
    const double px = fx - s_tf[21], py = fy - s_tf[22], mz = -s_tf[23];
    const double qx0 = s_tf[ 9]*px + s_tf[10]*py + s_tf[11]*mz, qx1 = s_tf[11];
    const double qy0 = s_tf[12]*px + s_tf[13]*py + s_tf[14]*mz, qy1 = s_tf[14];
    const double qz0 = s_tf[15]*px + s_tf[16]*py + s_tf[17]*mz, qz1 = s_tf[17];
    const double ux0 = s_tf[0]*qx0 + s_tf[1]*qy0 + s_tf[2], ux1 = s_tf[0]*qx1 + s_tf[1]*qy1;
    const double uy0 = s_tf[3]*qx0 + s_tf[4]*qy0 + s_tf[5], uy1 = s_tf[3]*qx1 + s_tf[4]*qy1;
    const double uz0 = s_tf[6]*qx0 + s_tf[7]*qy0 + s_tf[8], uz1 = s_tf[6]*qx1 + s_tf[7]*qy1;
    const double t0 = s_tf[18], t1 = s_tf[19], t2 = s_tf[20];

    const double DXD = (double)0.8f;
    const double LOX = (double)(-50.8f) - DXD*0.5;
    const double LOY = LOX;
    const double DZD = 20.0;
    const double LOZ = -10.0;

    kept = false; vox = 0;
    if (l < Dd) {
        double fz = 4.0 + (double)l;
        double qz = qz0 + qz1*fz;
        double sx = qz*(ux0 + ux1*fz) + t0;
        double sy = qz*(uy0 + uy1*fz) + t1;
        double sz = qz*(uz0 + uz1*fz) + t2;
        int gx = (int)((sx - LOX) / DXD);
        int gy = (int)((sy - LOY) / DXD);
        int gz = (int)((sz - LOZ) / DZD);
        kept = (gx>=0) & (gx<NXX) & (gy>=0) & (gy<NYY) & (gz>=0) & (gz<NZZ);
        vox  = (((b*NZZ + gz)*NYY + gy)*NXX + gx);
    }
}

// ---------------- kernel P: prep = x->bf16 fragments + Wd->bf16 + tf + hist=0 -----
__global__ __launch_bounds__(256) void prep_kernel(
    const float* __restrict__ rots, const float* __restrict__ trans,
    const float* __restrict__ intrins, const float* __restrict__ post_rots,
    const float* __restrict__ post_trans, const float* __restrict__ Wd,
    const float* __restrict__ x,
    double* __restrict__ tf, unsigned short* __restrict__ WdB,
    unsigned short* __restrict__ xB, int* __restrict__ hist)
{
    const int t = threadIdx.x;
    if (blockIdx.x < 2112) {
        __shared__ float s_x[64*68];          // stride 68: 16B-aligned float4 cells
        const int p    = blockIdx.x;
        const int bn   = p / 88;
        const int r    = p % 88;
        const int kg   = r / 11;          // 0..7 (64 k each)
        const int tile = r % 11;
        const int pix0 = tile * 64;

        const float* src = x + ((size_t)bn*CIN + kg*64)*NPIX + pix0;
        #pragma unroll
        for (int i = 0; i < 4; i++) {
            int idx = i*256 + t;          // 0..1023
            int k   = idx >> 4;
            int px4 = (idx & 15) * 4;
            float4 v = *(const float4*)&src[(size_t)k*NPIX + px4];
            *(float4*)&s_x[k*68 + px4] = v;
        }
        __syncthreads();

        const int px  = t & 63;
        #pragma unroll
        for (int pass = 0; pass < 2; pass++) {
            int k8l = (t >> 6) + 4*pass;          // 0..7
            unsigned pk[4];
            #pragma unroll
            for (int i = 0; i < 4; i++) {
                float a = s_x[(k8l*8 + 2*i    )*68 + px];
                float c = s_x[(k8l*8 + 2*i + 1)*68 + px];
                pk[i] = (unsigned)f2bf(a) | ((unsigned)f2bf(c) << 16);
            }
            unsigned* dst = (unsigned*)&xB[(((size_t)(bn*64 + kg*8 + k8l))*NPIX + pix0 + px)*8];
            *(uint4*)dst = make_uint4(pk[0], pk[1], pk[2], pk[3]);
        }
    } else if (blockIdx.x < 2368) {
        int b2 = blockIdx.x - 2112;
        int idx = b2*256 + t;
        if (idx < 128*CIN) {
            int o = idx / CIN;
            WdB[idx] = (o < NO) ? f2bf(Wd[idx]) : (unsigned short)0;
        }
        if (b2 == 0 && t < B_*N_) {
            int bn = t;
            double k[9], pr[9], r[9], ik[9], ipr[9], c[9];
            for (int i=0;i<9;i++) { k[i]=intrins[bn*9+i]; pr[i]=post_rots[bn*9+i]; r[i]=rots[bn*9+i]; }
            inv3(k, ik);
            inv3(pr, ipr);
            for (int i=0;i<3;i++)
                for (int j=0;j<3;j++) {
                    double s = 0.0;
                    for (int kk=0;kk<3;kk++) s += r[i*3+kk]*ik[kk*3+j];
                    c[i*3+j] = s;
                }
            double* o = tf + bn*24;
            for (int i=0;i<9;i++) o[i]   = c[i];
            for (int i=0;i<9;i++) o[9+i] = ipr[i];
            for (int i=0;i<3;i++) o[18+i] = (double)trans[bn*3+i];
            for (int i=0;i<3;i++) o[21+i] = (double)post_trans[bn*3+i];
        }
    } else {
        // zero hist (65536 ints over 256 blocks)
        int b3 = blockIdx.x - 2368;
        hist[b3*256 + t] = 0;
    }
}

// ---------------- kernel GG: fused bf16 MFMA GEMM || geometry+hist ----------------
// blocks 0..1055: gemm with TWO-PASS weight staging (16 rows / 16.6 KB LDS at a
// time -> 8 blocks/CU co-residency for the geom path). blocks 1056..5279:
// geometry + hist (fabric-atomic-bound). Co-scheduled waves hide atomic latency.
__global__ __launch_bounds__(256) void gemm_geom_kernel(
    const unsigned short* __restrict__ xB, const unsigned short* __restrict__ WdB,
    const float* __restrict__ bd, const double* __restrict__ tf,
    float* __restrict__ featD, float* __restrict__ featB,
    int* __restrict__ hist, int* __restrict__ rank_arr)
{
    __shared__ unsigned short s_wd[16*WSTRIDE];   // 16.6 KB (gemm path)
    __shared__ double s_tf[24];                   // geom path

    const int t    = threadIdx.x;
    const int l    = t & 63;
    const int wv   = t >> 6;

    if (blockIdx.x < GEMM_BLOCKS) {
        // ================= GEMM path (two-pass weight staging) =================
        const int col  = l & 15;
        const int quad = l >> 4;
        const int xcd = blockIdx.x & 7;
        const int q   = blockIdx.x >> 3;
        const int s   = q & 3;               // osplit
        const int pg  = q >> 2;
        const int p   = pg*8 + xcd;          // 0..263
        const int bn   = p / 11;
        const int tile = p % 11;
        const int pix0 = tile * 64;

        const int pix = pix0 + wv*16 + col;
        const unsigned short* xbase = xB + (((size_t)(bn*64))*NPIX)*8;

        f32x4 acc[2];
        acc[0] = (f32x4){0.f,0.f,0.f,0.f};
        acc[1] = (f32x4){0.f,0.f,0.f,0.f};

        #pragma unroll
        for (int half = 0; half < 2; half++) {
            // stage 16 o-rows (full K): thread -> row t>>4, 64B chunk (t&15)
            {
                const int o  = t >> 4;           // 0..15
                const int c  = t & 15;           // 64B chunk
                const unsigned short* srcw = WdB + (size_t)(s*32 + half*16 + o)*CIN + c*32;
                uint4 v0 = *(const uint4*)(srcw + 0);
                uint4 v1 = *(const uint4*)(srcw + 8);
                uint4 v2 = *(const uint4*)(srcw + 16);
                uint4 v3 = *(const uint4*)(srcw + 24);
                unsigned short* dstw = &s_wd[o*WSTRIDE + c*32];
                *(uint4*)(dstw + 0)  = v0;
                *(uint4*)(dstw + 8)  = v1;
                *(uint4*)(dstw + 16) = v2;
                *(uint4*)(dstw + 24) = v3;
            }
            __syncthreads();

            #pragma unroll
            for (int ks = 0; ks < 16; ks++) {
                const int k8 = ks*4 + quad;
                short8 bfr = *(const short8*)&xbase[((size_t)k8*NPIX + pix)*8];
                short8 afr = *(const short8*)&s_wd[col*WSTRIDE + ks*32 + quad*8];
                acc[half] = __builtin_amdgcn_mfma_f32_16x16x32_bf16(afr, bfr, acc[half], 0, 0, 0);
            }
            __syncthreads();
        }

        const size_t prow = (size_t)(bn*NPIX + pix);
        #pragma unroll
        for (int j = 0; j < 2; j++) {
            #pragma unroll
            for (int rr = 0; rr < 4; rr++) {
                int o = (2*s + j)*16 + quad*4 + rr;
                if (o < Dd) {
                    featD[prow*DSTR + o] = acc[j][rr] + bd[o];
                } else if (o < NO) {
                    featB[prow*CT + (o - Dd)] = acc[j][rr] + bd[o];
                }
            }
        }
    } else {
        // ================= geometry + hist path =================
        const int bid2 = blockIdx.x - GEMM_BLOCKS;                 // 0..4223
        const int bid  = (bid2 & 7) * 528 + (bid2 >> 3);           // XCD locality
        const int bn  = bid / 176;
        const int pix = (bid % 176)*4 + wv;
        const int b   = bn / N_;

        if (t < 24) s_tf[t] = tf[bn*24 + t];
        __syncthreads();

        bool kept; int vox;
        geom_lane(s_tf, b, pix, l, kept, vox);
        if (kept) {
            int rank = atomicAdd(&hist[vox], 1);
            rank_arr[(size_t)(bn*NPIX + pix)*Dd + l] = rank;
        }
    }
}

// ---------------- scan1: local scan (also zeroes scat, 64KB/block) ----------------
__global__ __launch_bounds__(256) void scan1_kernel(const int* __restrict__ hist,
                                                    int* __restrict__ offs,
                                                    int* __restrict__ bsum,
                                                    float4* __restrict__ scat4) {
    __shared__ int s[256];
    const int t = threadIdx.x;
    const int i = blockIdx.x*256 + t;
    int val = hist[i];
    s[t] = val;
    __syncthreads();

    // zero 64KB of scat while the scan barriers churn (16 float4 per thread)
    {
        float4 z = make_float4(0.f, 0.f, 0.f, 0.f);
        float4* dst = scat4 + (size_t)blockIdx.x*4096 + t;
        #pragma unroll
        for (int j = 0; j < 16; j++) dst[j*256] = z;
    }

    #pragma unroll
    for (int off = 1; off < 256; off <<= 1) {
        __syncthreads();
        int u = (t >= off) ? s[t-off] : 0;
        __syncthreads();
        s[t] += u;
    }
    __syncthreads();
    offs[i] = s[t] - val;                  // block-local exclusive
    if (t == 255) bsum[blockIdx.x] = s[255];
}

__global__ __launch_bounds__(256) void scan2_kernel(int* __restrict__ bsum,
                                                    int* __restrict__ np) {
    __shared__ int s[256];
    const int t = threadIdx.x;
    int v = bsum[t];
    s[t] = v;
    __syncthreads();
    #pragma unroll
    for (int off = 1; off < 256; off <<= 1) {
        int u = (t >= off) ? s[t-off] : 0;
        __syncthreads();
        s[t] += u;
        __syncthreads();
    }
    bsum[t] = s[t] - v;
    if (t == 255) np[0] = s[255];
}

// ---------------- kernel S2: softmax + geometry + atomic-free record scatter --------
__global__ __launch_bounds__(256) void sm_scatter_kernel(
    const float* __restrict__ featD, const double* __restrict__ tf,
    const int* __restrict__ offs, const int* __restrict__ bsum,
    const int* __restrict__ rank_arr, uint2* __restrict__ rec)
{
    __shared__ double s_tf[24];
    const int bid = (blockIdx.x & 7) * 528 + (blockIdx.x >> 3);   // XCD locality
    const int t   = threadIdx.x;
    const int l   = t & 63;
    const int wv  = t >> 6;
    const int bn  = bid / 176;
    const int pix = (bid % 176)*4 + wv;
    const int b   = bn / N_;

    if (t < 24) s_tf[t] = tf[bn*24 + t];
    __syncthreads();

    const size_t prow = (size_t)(bn*NPIX + pix);

    // ---- softmax across lanes (d = lane, 41 active) ----
    float logit = (l < Dd) ? featD[prow*DSTR + l] : -3.0e38f;
    float mm = logit;
    #pragma unroll
    for (int off = 32; off > 0; off >>= 1) mm = fmaxf(mm, __shfl_xor(mm, off));
    float e = (l < Dd) ? expf(logit - mm) : 0.0f;
    float ssum = e;
    #pragma unroll
    for (int off = 32; off > 0; off >>= 1) ssum += __shfl_xor(ssum, off);
    const float wgt = e / ssum;

    // ---- geometry + position from offs + bsum + rank (no atomics) ----
    bool kept; int vox;
    geom_lane(s_tf, b, pix, l, kept, vox);
    if (kept) {
        int pos = offs[vox] + bsum[vox >> 8] + rank_arr[prow*Dd + l];
        unsigned pk = ((unsigned)vox << 15) | (unsigned)prow;
        rec[pos] = make_uint2(pk, __float_as_uint(wgt));
    }
}

// ---------------- kernel E: balanced segmented gather -> scat[vox][ct] ----------------
__global__ __launch_bounds__(256) void gather_kernel(
    const uint2* __restrict__ rec, const int* __restrict__ np,
    const float* __restrict__ featB, float* __restrict__ scat)
{
    const int bid = (blockIdx.x & 7) * 339 + (blockIdx.x >> 3);   // XCD locality
    const int t  = threadIdx.x;
    const int wv = t >> 6;
    const int l  = t & 63;
    const int chunk = bid * 4 + wv;
    const int base  = chunk * 64;
    const int Np = np[0];                  // total valid points
    if (base >= Np) return;
    int cnt = Np - base; if (cnt > 64) cnt = 64;

    unsigned pk = 0; float w = 0.0f;
    if (l < cnt) { uint2 r = rec[base + l]; pk = r.x; w = __uint_as_float(r.y); }
    unsigned pkm = __shfl(pk, (l == 0) ? 0 : (l - 1));
    unsigned long long starts =
        __ballot((l > 0) && (l < cnt) && ((pk >> 15) != (pkm >> 15)));

    unsigned long long m = starts;
    int rs = 0;
    while (rs < cnt) {
        int re = m ? (__ffsll((unsigned long long)m) - 1) : cnt;
        if (m) m &= m - 1;
        float acc = 0.0f;
        for (int j = rs; j < re; j++) {
            unsigned pkj = __shfl(pk, j);
            float    wj  = __shfl(w, j);
            unsigned id  = pkj & 0x7FFFu;
            acc += wj * featB[(size_t)id * CT + l];
        }
        unsigned vrun = __shfl(pk, rs) >> 15;
        float* dst = scat + (size_t)vrun * CT + l;
        if (rs == 0 || re == cnt) {
            unsafeAtomicAdd(dst, acc);      // run may continue in adjacent chunk
        } else {
            *dst = acc;                     // voxel wholly owned by this chunk
        }
        rs = re;
    }
}

// ---------------- kernel F: transpose (b,pix,ct) -> (b,ct,pix) ----------------
__global__ __launch_bounds__(256) void transpose_k(const float* __restrict__ scat,
                                                   float* __restrict__ out) {
    __shared__ float tile[64][65];
    int b  = blockIdx.x >> 8;
    int t0 = (blockIdx.x & 255) * 64;
    const float* src = scat + (size_t)b * (NYY*NXX) * CT;
    #pragma unroll
    for (int i=0;i<16;i++) {
        int idx = threadIdx.x + i*256;
        int p = idx >> 6, c = idx & 63;
        tile[p][c] = src[(size_t)(t0+p)*CT + c];
    }
    __syncthreads();
    float* dst = out + (size_t)b * CT * (NYY*NXX);
    #pragma unroll
    for (int i=0;i<16;i++) {
        int idx = threadIdx.x + i*256;
        int c = idx >> 6, p = idx & 63;
        dst[(size_t)c*(NYY*NXX) + t0 + p] = tile[p][c];
    }
}

// ---------------- launcher ----------------
extern "C" void kernel_launch(void* const* d_in, const int* in_sizes, int n_in,
                              void* d_out, int out_size, void* d_ws, size_t ws_size,
                              hipStream_t stream) {
    const float* x          = (const float*)d_in[0];
    const float* rots       = (const float*)d_in[1];
    const float* trans      = (const float*)d_in[2];
    const float* intrins    = (const float*)d_in[3];
    const float* post_rots  = (const float*)d_in[4];
    const float* post_trans = (const float*)d_in[5];
    const float* Wd         = (const float*)d_in[6];
    const float* bd         = (const float*)d_in[7];
    float* out = (float*)d_out;

    char* ws = (char*)d_ws;
    float*          featB  = (float*)ws;          ws += (size_t)B_*N_*NPIX*CT*4;    // 4.33 MB
    float*          featD  = (float*)ws;          ws += (size_t)B_*N_*NPIX*DSTR*4;  // 3.25 MB
    char*           Xreg   = ws;                  ws += (size_t)B_*N_*CIN*NPIX*2;   // 17.3 MB (xB, then scat)
    int*            rank_a = (int*)ws;            ws += (size_t)NPTS*4;             // 2.77 MB
    uint2*          rec    = (uint2*)ws;          ws += (size_t)NPTS*8;             // 5.54 MB
    int*            hist   = (int*)ws;            ws += (size_t)TOT*4;              // 0.26 MB
    int*            offs   = (int*)ws;            ws += (size_t)TOT*4;              // 0.26 MB
    int*            bsum   = (int*)ws;            ws += 256*4;
    int*            np     = (int*)ws;            ws += 256;
    double*         tf     = (double*)ws;         ws += (size_t)B_*N_*24*8;         // 4.6 KB
    unsigned short* WdB    = (unsigned short*)ws; ws += (size_t)128*CIN*2;          // 0.13 MB

    unsigned short* xB   = (unsigned short*)Xreg;
    float*          scat = (float*)Xreg;   // reuses xB region after fused kernel

    prep_kernel<<<2624, 256, 0, stream>>>(rots, trans, intrins, post_rots, post_trans,
                                          Wd, x, tf, WdB, xB, hist);
    gemm_geom_kernel<<<GEMM_BLOCKS + GEOM_BLOCKS, 256, 0, stream>>>(
        xB, WdB, bd, tf, featD, featB, hist, rank_a);
    scan1_kernel<<<TOT/256, 256, 0, stream>>>(hist, offs, bsum, (float4*)scat);
    scan2_kernel<<<1, 256, 0, stream>>>(bsum, np);
    sm_scatter_kernel<<<B_*N_*176, 256, 0, stream>>>(featD, tf, offs, bsum, rank_a, rec);
    gather_kernel<<<2712, 256, 0, stream>>>(rec, np, featB, scat);
    transpose_k<<<B_*(NYY*NXX/64), 256, 0, stream>>>(scat, out);
}